// Round 8
// baseline (5270.186 us; speedup 1.0000x reference)
//
#include <hip/hip_runtime.h>
#include <math.h>

#define NSW 12  // convergence-verified budget (R2/R5/R6/R7: absmax at bf16 floor)

typedef float v2 __attribute__((ext_vector_type(2)));  // -> v_pk_*_f32 on CDNA

__device__ __forceinline__ float bperm_f(int addr4, float v) {
    return __int_as_float(__builtin_amdgcn_ds_bpermute(addr4, __float_as_int(v)));
}

// One-sided (Hestenes) Jacobi, circle-method tournament (R2/R5/R7-verified).
// R8: TWO matrices per 256-thread workgroup (2 waves each) to break the
// observed ~7-8 workgroup/CU occupancy ceiling, + packed-f32 (v2) dot/update
// to halve the dominant VALU cost. Per-matrix main loop structure identical
// to R7. LDS overlaid: main-phase gram buffer reuses the epilogue region;
// 3328 B per matrix, 6656 B per block.
__global__ __launch_bounds__(256, 4) void logeig_kernel(
    const float* __restrict__ Xg, float* __restrict__ out)
{
    // per-matrix region: 832 floats. main: gb[0..255] ([parity][wave][64]).
    // epilogue: Wc[0..767] ([64][12], 8-col chunks), hl[768..831].
    __shared__ __align__(16) float smem[2 * 832];

    const int tid = threadIdx.x;
    const int mb  = tid >> 7;          // matrix within block
    const int w   = (tid >> 6) & 1;    // wave half: rows [32w, 32w+32)
    const int l   = tid & 63;          // owned column
    float* const base = smem + mb * 832;
    float* const gb   = base;          // gram exchange: par*128 + w*64 + l
    const size_t bm   = (size_t)blockIdx.x * 2 + mb;

    // ---- load rows [32w,32w+32) of column l (X symmetric -> row l span) ----
    v2 x2[16];
    {
        const float4* __restrict__ Xb4 =
            (const float4*)(Xg + bm * 4096 + (size_t)l * 64 + 32 * w);
        #pragma unroll
        for (int q = 0; q < 8; ++q) {
            float4 v = Xb4[q];
            x2[2 * q + 0] = (v2){v.x, v.y};
            x2[2 * q + 1] = (v2){v.z, v.w};
        }
    }

    // canonical packed self-dot (identical formula on every copy)
    #define SELFDOT(res)                                              \
        {                                                             \
            v2 a0 = {0.f,0.f}, a1 = {0.f,0.f},                        \
               a2 = {0.f,0.f}, a3 = {0.f,0.f};                        \
            _Pragma("unroll")                                         \
            for (int k = 0; k < 16; k += 4) {                         \
                a0 += x2[k + 0] * x2[k + 0];                          \
                a1 += x2[k + 1] * x2[k + 1];                          \
                a2 += x2[k + 2] * x2[k + 2];                          \
                a3 += x2[k + 3] * x2[k + 3];                          \
            }                                                         \
            const v2 sv = (a0 + a1) + (a2 + a3);                      \
            res = sv.x + sv.y;                                        \
        }

    // ---- initial squared norm: half-norms combined canonically ----
    float d;
    {
        float p; SELFDOT(p);
        gb[w * 64 + l] = p;
        __syncthreads();
        d = gb[l] + gb[64 + l];
    }

    // ---- tournament state (identical formulas to R2/R5/R7) ----
    const int m  = l - 1;                       // label; -1 for fixed player col 0
    int pm = (l == 0) ? 0 : ((63 - m) % 63);    // (r - m) mod 63 at r=0
    int p0 = 0;                                 // 32*r mod 63

    for (int sweep = 0; sweep < NSW; ++sweep) {
        for (int r = 0; r < 63; ++r) {
            const int prt  = (l == 0) ? (p0 + 1)
                                      : ((pm == m) ? 0 : (pm + 1));
            const int prt4 = prt << 2;

            // fetch partner half-column + packed Gram partial (32 rows)
            v2 xp2[16];
            v2 a0 = {0.f,0.f}, a1 = {0.f,0.f}, a2 = {0.f,0.f}, a3 = {0.f,0.f};
            #pragma unroll
            for (int k = 0; k < 16; k += 4) {
                xp2[k+0].x = bperm_f(prt4, x2[k+0].x);
                xp2[k+0].y = bperm_f(prt4, x2[k+0].y);
                xp2[k+1].x = bperm_f(prt4, x2[k+1].x);
                xp2[k+1].y = bperm_f(prt4, x2[k+1].y);
                xp2[k+2].x = bperm_f(prt4, x2[k+2].x);
                xp2[k+2].y = bperm_f(prt4, x2[k+2].y);
                xp2[k+3].x = bperm_f(prt4, x2[k+3].x);
                xp2[k+3].y = bperm_f(prt4, x2[k+3].y);
                a0 += x2[k + 0] * xp2[k + 0];
                a1 += x2[k + 1] * xp2[k + 1];
                a2 += x2[k + 2] * xp2[k + 2];
                a3 += x2[k + 3] * xp2[k + 3];
            }
            const v2 sv = (a0 + a1) + (a2 + a3);
            const float gp = sv.x + sv.y;            // this wave's half of gamma
            const float dq = bperm_f(prt4, d);       // partner's full norm

            gb[(r & 1) * 128 + w * 64 + l] = gp;
            __syncthreads();
            const float go = gb[(r & 1) * 128 + (1 - w) * 64 + l];
            const float g  = gp + go;                // commutative -> bit-identical

            const bool lo = l < prt;
            const bool ok = fabsf(g) > 1e-30f;

            // angle from the LO column's perspective (identical on all copies)
            const float num  = lo ? (dq - d) : (d - dq);
            const float zeta = num / (2.f * g);
            const float az   = fabsf(zeta);
            float tl = 1.f / (az + sqrtf(fmaf(az, az, 1.f)));
            tl = (zeta >= 0.f) ? tl : -tl;           // lo-side t
            float tn = lo ? tl : -tl;                // own signed t (hi negates)
            tn = ok ? tn : 0.f;
            const float c = rsqrtf(fmaf(tn, tn, 1.f));
            const float s = c * tn;

            // Rutishauser norm update (identical on both waves of the matrix)
            d = fmaf(-tn, g, d);

            // packed half-column update: u' = c*u - s*u_partner
            #pragma unroll
            for (int k = 0; k < 16; ++k)
                x2[k] = c * x2[k] - s * xp2[k];

            // advance tournament state
            pm = (pm + 1 == 63) ? 0 : (pm + 1);
            p0 += 32; if (p0 >= 63) p0 -= 63;
        }

        // sweep boundary: resync squared norm (parity-0 gb region reused)
        float p; SELFDOT(p);
        __syncthreads();                        // rotations' gb reads done
        gb[w * 64 + l] = p;
        __syncthreads();
        d = gb[l] + gb[64 + l];
    }
    #undef SELFDOT

    // ---- epilogue: out = sum_c h_c w_c w_c^T (8-col chunks, spill-free) ----
    const float alpha = fmaxf(d, 1e-12f);
    const float h = 0.5f * logf(alpha) / alpha;
    float* const Wc = base;          // [64][12]
    float* const hl = base + 768;    // [64] — outside gb's 256 floats, safe now
    if (w == 0) hl[l] = h;           // identical value on both waves

    const int cg = l >> 3;           // chunk containing this lane's column
    const int cc = l & 7;            // column index within chunk
    float* __restrict__ outb = out + bm * 4096;

    for (int rh = 0; rh < 2; ++rh) {
        float acc[16];
        #pragma unroll
        for (int k = 0; k < 16; ++k) acc[k] = 0.f;
        const int rbase = 32 * w + 16 * rh;     // output rows this pass

        for (int gi = 0; gi < 8; ++gi) {
            __syncthreads();   // Wc WAR (and gb->Wc transition on first iter)
            if (cg == gi) {
                #pragma unroll
                for (int k = 0; k < 16; ++k) {
                    Wc[(32 * w + 2 * k + 0) * 12 + cc] = x2[k].x;
                    Wc[(32 * w + 2 * k + 1) * 12 + cc] = x2[k].y;
                }
            }
            __syncthreads();

            float r0[8];
            #pragma unroll
            for (int j = 0; j < 8; ++j)
                r0[j] = Wc[l * 12 + j] * hl[gi * 8 + j];

            #pragma unroll
            for (int k = 0; k < 16; ++k) {
                const int row = rbase + k;
                const float4 wa = *(const float4*)&Wc[row * 12 + 0];
                const float4 wb = *(const float4*)&Wc[row * 12 + 4];
                acc[k] += fmaf(wa.x, r0[0], fmaf(wa.y, r0[1],
                               fmaf(wa.z, r0[2], wa.w * r0[3])))
                        + fmaf(wb.x, r0[4], fmaf(wb.y, r0[5],
                               fmaf(wb.z, r0[6], wb.w * r0[7])));
            }
        }

        // coalesced stores: for fixed row, lanes l=0..63 write 256B contiguous
        #pragma unroll
        for (int k = 0; k < 16; ++k)
            outb[(size_t)(rbase + k) * 64 + l] = acc[k];
    }
}

extern "C" void kernel_launch(void* const* d_in, const int* in_sizes, int n_in,
                              void* d_out, int out_size, void* d_ws, size_t ws_size,
                              hipStream_t stream)
{
    const float* X = (const float*)d_in[0];
    float* out = (float*)d_out;
    const int B = in_sizes[0] / 4096;   // 8192 matrices of 64x64 fp32
    logeig_kernel<<<dim3(B / 2), dim3(256), 0, stream>>>(X, out);
}